// Round 1
// baseline (224.891 us; speedup 1.0000x reference)
//
#include <hip/hip_runtime.h>

// SpecialFlatten: out_f2[b][i][j] = in_f2[b][j][i], where f2 = adjacent float pair.
// B=32, R=2048, C=512 (C2=256 float2 columns). Batched 2048x256 float2 transpose.

#define TILE 64   // tile edge in float2 elements

__global__ __launch_bounds__(256) void transpose_pair_kernel(
    const float* __restrict__ x, float* __restrict__ y, int R, int C2) {
    // Component-split LDS tiles: odd row stride (65 words) -> conflict-free
    __shared__ float sx[TILE][TILE + 1];
    __shared__ float sy[TILE][TILE + 1];

    const int tx = threadIdx.x;   // 0..31
    const int ty = threadIdx.y;   // 0..7

    const int c0 = blockIdx.x * TILE;   // pair-column tile origin
    const int j0 = blockIdx.y * TILE;   // row tile origin
    const int b  = blockIdx.z;

    const size_t base_f = (size_t)b * R * (size_t)(C2 * 2);  // floats

    // ---- Load: 16 B/lane. float4 = IN_f2[j][c0+2tx], IN_f2[j][c0+2tx+1]
    const float4* inp = (const float4*)(x + base_f);
    const int row_f4 = C2 / 2;           // float4s per input row
    #pragma unroll
    for (int k = 0; k < 8; ++k) {
        const int jl = ty + 8 * k;       // 0..63
        const int j  = j0 + jl;
        float4 v = inp[(size_t)j * row_f4 + (c0 >> 1) + tx];
        sx[jl][2 * tx]     = v.x;
        sy[jl][2 * tx]     = v.y;
        sx[jl][2 * tx + 1] = v.z;
        sy[jl][2 * tx + 1] = v.w;
    }
    __syncthreads();

    // ---- Store: 16 B/lane. float4 = OUT_f2[c][j0+2tx], OUT_f2[c][j0+2tx+1]
    float4* outp = (float4*)(y + base_f);
    const int orow_f4 = R / 2;           // float4s per output row
    #pragma unroll
    for (int k = 0; k < 8; ++k) {
        const int cl = ty + 8 * k;       // 0..63
        const int c  = c0 + cl;
        float4 v;
        v.x = sx[2 * tx][cl];
        v.y = sy[2 * tx][cl];
        v.z = sx[2 * tx + 1][cl];
        v.w = sy[2 * tx + 1][cl];
        outp[(size_t)c * orow_f4 + (j0 >> 1) + tx] = v;
    }
}

extern "C" void kernel_launch(void* const* d_in, const int* in_sizes, int n_in,
                              void* d_out, int out_size, void* d_ws, size_t ws_size,
                              hipStream_t stream) {
    const float* x = (const float*)d_in[0];
    float* y = (float*)d_out;

    const int B = 32, R = 2048, C = 512;
    const int C2 = C / 2;  // 256 float2 columns

    dim3 block(32, 8, 1);
    dim3 grid(C2 / TILE, R / TILE, B);  // (4, 32, 32)
    transpose_pair_kernel<<<grid, block, 0, stream>>>(x, y, R, C2);
}

// Round 3
// 216.677 us; speedup vs baseline: 1.0379x; 1.0379x over previous
//
#include <hip/hip_runtime.h>

// SpecialFlatten: out_f2[b][i][j] = in_f2[b][j][i], where f2 = adjacent float pair.
// B=32, R=2048, C=512 (C2=256 float2 columns). Batched 2048x256 float2 transpose.
// Pure streaming permutation: 128 MiB read + 128 MiB write, zero reuse.

#define TILE 64   // tile edge in float2 elements

// Native clang vector type: required by __builtin_nontemporal_load/store
// (HIP_vector_type float4 is a struct and is rejected).
typedef float fx4 __attribute__((ext_vector_type(4)));

__global__ __launch_bounds__(256) void transpose_pair_kernel(
    const float* __restrict__ x, float* __restrict__ y, int R, int C2) {
    // Component-split LDS tiles: odd row stride (65 words) -> <=2-way bank
    // aliasing on both phases (free on gfx950, m136).
    __shared__ float sx[TILE][TILE + 1];
    __shared__ float sy[TILE][TILE + 1];

    const int tx = threadIdx.x;   // 0..31
    const int ty = threadIdx.y;   // 0..7

    const int c0 = blockIdx.x * TILE;   // pair-column tile origin
    const int j0 = blockIdx.y * TILE;   // row tile origin
    const int b  = blockIdx.z;

    const size_t base_f = (size_t)b * R * (size_t)(C2 * 2);  // floats

    // ---- Load phase: issue all 8 16B loads first (8 outstanding vmem/wave),
    // then drain into LDS.
    const fx4* inp = (const fx4*)(x + base_f);
    const int row_f4 = C2 / 2;           // float4s per input row
    fx4 v[8];
    #pragma unroll
    for (int k = 0; k < 8; ++k) {
        const int j = j0 + ty + 8 * k;
        v[k] = __builtin_nontemporal_load(&inp[(size_t)j * row_f4 + (c0 >> 1) + tx]);
    }
    #pragma unroll
    for (int k = 0; k < 8; ++k) {
        const int jl = ty + 8 * k;       // 0..63
        sx[jl][2 * tx]     = v[k].x;
        sy[jl][2 * tx]     = v[k].y;
        sx[jl][2 * tx + 1] = v[k].z;
        sy[jl][2 * tx + 1] = v[k].w;
    }
    __syncthreads();

    // ---- Store phase: gather all 8 float4 from LDS, then issue 8 16B stores
    // back-to-back.
    fx4* outp = (fx4*)(y + base_f);
    const int orow_f4 = R / 2;           // float4s per output row
    fx4 w[8];
    #pragma unroll
    for (int k = 0; k < 8; ++k) {
        const int cl = ty + 8 * k;       // 0..63
        w[k].x = sx[2 * tx][cl];
        w[k].y = sy[2 * tx][cl];
        w[k].z = sx[2 * tx + 1][cl];
        w[k].w = sy[2 * tx + 1][cl];
    }
    #pragma unroll
    for (int k = 0; k < 8; ++k) {
        const int c = c0 + ty + 8 * k;
        __builtin_nontemporal_store(w[k], &outp[(size_t)c * orow_f4 + (j0 >> 1) + tx]);
    }
}

extern "C" void kernel_launch(void* const* d_in, const int* in_sizes, int n_in,
                              void* d_out, int out_size, void* d_ws, size_t ws_size,
                              hipStream_t stream) {
    const float* x = (const float*)d_in[0];
    float* y = (float*)d_out;

    const int B = 32, R = 2048, C = 512;
    const int C2 = C / 2;  // 256 float2 columns

    dim3 block(32, 8, 1);
    dim3 grid(C2 / TILE, R / TILE, B);  // (4, 32, 32)
    transpose_pair_kernel<<<grid, block, 0, stream>>>(x, y, R, C2);
}